// Round 7
// baseline (195.041 us; speedup 1.0000x reference)
//
#include <hip/hip_runtime.h>
#include <hip/hip_bf16.h>

// Shapes: B=8 C=512 T=32 H=W=7 P=49 N=8 E=64 K_WIN=7
// x: (B,C,T,H,W) fp32; out same fp32.
// BatchNorm folded into GEMM weights; N-dim packed to 256*49=12544 cols.
// GEMMs are LDS-free (L2-resident operands): per-wave 64x64 tiles, reg frags.

typedef float f32x4 __attribute__((ext_vector_type(4)));
typedef float f32x2 __attribute__((ext_vector_type(2)));
typedef short s16x8 __attribute__((ext_vector_type(8)));
typedef short s16x4 __attribute__((ext_vector_type(4)));
typedef __bf16 bf16x8 __attribute__((ext_vector_type(8)));

static __device__ __forceinline__ float bf2f(unsigned short u){
  union { unsigned int i; float f; } x; x.i = ((unsigned int)u) << 16; return x.f;
}
static __device__ __forceinline__ unsigned short f2bf(float f){
  union { __hip_bfloat16 h; unsigned short u; } x; x.h = __float2bfloat16(f); return x.u;
}
static __device__ __forceinline__ f32x4 mfma16(s16x8 a, s16x8 b, f32x4 c){
  return __builtin_amdgcn_mfma_f32_16x16x32_bf16(
      __builtin_bit_cast(bf16x8, a), __builtin_bit_cast(bf16x8, b), c, 0, 0, 0);
}

// ---------------- x -> Xt[bt*49+p][c] bf16  +  per-bt channel partial sums ----------------
__global__ __launch_bounds__(256) void xt_kernel(const float* __restrict__ x,
    unsigned short* __restrict__ Xt, float* __restrict__ partials){
  __shared__ unsigned short Xc[512][53];
  const int bt = blockIdx.x, b = bt >> 5, t = bt & 31, tid = threadIdx.x;
  const float* xb = x + (size_t)b*802816 + t*49;
  for (int i = tid; i < 512*49; i += 256){
    int c = i / 49, p = i - c*49;
    Xc[c][p] = f2bf(xb[(size_t)c*1568 + p]);
  }
  __syncthreads();
  unsigned short* dst = Xt + (size_t)bt*49*512;
  for (int i = tid; i < 49*64; i += 256){
    int p = i >> 6, c0 = (i & 63) << 3;
    s16x8 v;
    #pragma unroll
    for (int j = 0; j < 8; ++j) v[j] = (short)Xc[c0+j][p];
    *(s16x8*)(dst + p*512 + c0) = v;
  }
  for (int c = tid; c < 512; c += 256){
    float s1 = 0.f, s2 = 0.f;
    #pragma unroll 7
    for (int p = 0; p < 49; ++p){
      float f = bf2f(Xc[c][p]);
      s1 += f; s2 += f*f;
    }
    f32x2 o; o[0] = s1; o[1] = s2;
    *(f32x2*)(partials + ((size_t)bt*512 + c)*2) = o;
  }
}

// ---------------- reduce 256 partials -> scale/shift ----------------
__global__ __launch_bounds__(256) void stats2_kernel(const float* __restrict__ partials,
    const float* __restrict__ gamma, const float* __restrict__ beta,
    float* __restrict__ scale, float* __restrict__ shift){
  __shared__ float R1[4][64], R2[4][64];
  const int h = blockIdx.x, tid = threadIdx.x;
  const int r = tid >> 6, co = tid & 63;
  const int c = h*64 + co;
  float s1 = 0.f, s2 = 0.f;
  for (int k = r; k < 256; k += 4){
    f32x2 v = *(const f32x2*)(partials + ((size_t)k*512 + c)*2);
    s1 += v[0]; s2 += v[1];
  }
  R1[r][co] = s1; R2[r][co] = s2;
  __syncthreads();
  if (tid < 64){
    float t1 = R1[0][tid]+R1[1][tid]+R1[2][tid]+R1[3][tid];
    float t2 = R2[0][tid]+R2[1][tid]+R2[2][tid]+R2[3][tid];
    const int cc = h*64 + tid;
    const float inv = 1.f/12544.f;
    float mean = t1*inv;
    float var  = t2*inv - mean*mean;
    float sc = gamma[cc]*rsqrtf(var + 1e-5f);
    scale[cc] = sc;
    shift[cc] = beta[cc] - mean*sc;
  }
}

// ---------------- prep: pack weights (scale folded) + bias fold ----------------
__global__ __launch_bounds__(512) void prep_kernel(const float* __restrict__ Wq,
    const float* __restrict__ Wk, const float* __restrict__ Wv,
    const float* __restrict__ Wo, const float* __restrict__ bo,
    const float* __restrict__ bq, const float* __restrict__ bk,
    const float* __restrict__ bv,
    const float* __restrict__ scale, const float* __restrict__ shift,
    unsigned short* __restrict__ Wall, unsigned short* __restrict__ Wo2,
    float* __restrict__ bo_sum, float* __restrict__ biasAll){
  const int bid = blockIdx.x;
  if (bid < 2049){
    int i = bid*512 + threadIdx.x;
    if (i < 786432){
      const float* W = (i < 262144) ? Wq : (i < 524288 ? Wk : Wv);
      Wall[i] = f2bf(W[i & 262143] * scale[i & 511]);
    } else if (i < 1048576){
      int j = i - 786432;
      int c = j >> 9, k = j & 511, nn = k >> 6, e = k & 63;
      Wo2[j] = f2bf(Wo[((size_t)nn*512 + c)*64 + e] * 0.125f);
    } else if (i < 1049088){
      int c = i - 1048576;
      float s = 0.f;
      #pragma unroll
      for (int nn = 0; nn < 8; ++nn) s += bo[nn*512 + c];
      bo_sum[c] = s * 0.125f;
    }
  } else {
    const int row = (bid - 2049)*8 + (threadIdx.x >> 6);
    const int lane = threadIdx.x & 63;
    const float* W    = row < 512 ? Wq : (row < 1024 ? Wk : Wv);
    const float* bsrc = row < 512 ? bq : (row < 1024 ? bk : bv);
    const int r = row & 511;
    const float* Wr = W + (size_t)r*512;
    float s = 0.f;
    #pragma unroll
    for (int j = 0; j < 8; ++j) s += Wr[lane + 64*j]*shift[lane + 64*j];
    #pragma unroll
    for (int off = 32; off > 0; off >>= 1) s += __shfl_down(s, off);
    if (lane == 0) biasAll[row] = bsrc[r] + s;
  }
}

// ---------------- QKV GEMM: LDS-free, 4 waves x (64x64) = 128x128 block tile ----------------
// Wall'(1536x512) x Xt^T(512x12544). Frags straight from L2; no barriers.
__global__ __launch_bounds__(256,2) void qkv_gemm(const unsigned short* __restrict__ Wall,
    const unsigned short* __restrict__ Xt, const float* __restrict__ biasAll,
    unsigned short* __restrict__ Qg, unsigned short* __restrict__ Kg,
    unsigned short* __restrict__ Vg){
  const int bid = blockIdx.x;
  const int id = (bid & 7)*147 + (bid >> 3);   // 1176 = 8*147, bijective
  const int bm = id % 12, bn = id / 12;        // bm fastest: B panel reused block-to-block
  const int m0 = bm*128, n0 = bn*128;
  const int tid = threadIdx.x;
  const int w = __builtin_amdgcn_readfirstlane(tid >> 6);
  const int lane = tid & 63, l15 = lane & 15, g = lane >> 4, g4 = (lane >> 4)*4;
  const int wm = w >> 1, wn = w & 1;
  const unsigned short* Ab = Wall + (size_t)(m0 + wm*64 + l15)*512 + g*8;
  const unsigned short* Bb = Xt   + (size_t)(n0 + wn*64 + l15)*512 + g*8;
  f32x4 acc[4][4];
  #pragma unroll
  for (int mi = 0; mi < 4; ++mi)
    #pragma unroll
    for (int ni = 0; ni < 4; ++ni) acc[mi][ni] = 0.f;
  #pragma unroll 4
  for (int ks = 0; ks < 16; ++ks){
    s16x8 Af[4], Bf[4];
    #pragma unroll
    for (int mi = 0; mi < 4; ++mi) Af[mi] = *(const s16x8*)(Ab + mi*8192 + ks*32);
    #pragma unroll
    for (int ni = 0; ni < 4; ++ni) Bf[ni] = *(const s16x8*)(Bb + ni*8192 + ks*32);
    #pragma unroll
    for (int mi = 0; mi < 4; ++mi)
      #pragma unroll
      for (int ni = 0; ni < 4; ++ni)
        acc[mi][ni] = mfma16(Af[mi], Bf[ni], acc[mi][ni]);
  }
  // epilogue: rows -> (which, head, e); cols -> (bt, p) packed
  const int qb = bm*2 + wm;            // 0..23
  const int which = qb >> 3, n = qb & 7;
  f32x4 bb[4];
  #pragma unroll
  for (int mi = 0; mi < 4; ++mi)
    bb[mi] = *(const f32x4*)(biasAll + qb*64 + mi*16 + g4);
  #pragma unroll
  for (int ni = 0; ni < 4; ++ni){
    const int col = n0 + wn*64 + ni*16 + l15;
    const int btc = col / 49, p = col - btc*49;
    const size_t bnt = ((size_t)((btc >> 5)*8 + n)*32 + (btc & 31));
    #pragma unroll
    for (int mi = 0; mi < 4; ++mi){
      const int e0 = mi*16 + g4;
      f32x4 v = acc[mi][ni] + bb[mi];
      if (which == 0) v *= 1.4426950408889634f;
      if (which < 2){
        s16x4 u;
        #pragma unroll
        for (int r = 0; r < 4; ++r) u[r] = (short)f2bf(v[r]);
        *(s16x4*)((which == 0 ? Qg : Kg) + (bnt*49 + p)*64 + e0) = u;
      } else {
        #pragma unroll
        for (int r = 0; r < 4; ++r)
          Vg[bnt*3328 + (size_t)(e0 + r)*52 + p] = f2bf(v[r]);
      }
    }
  }
}

// ---------------- local attention (MFMA, online softmax in registers) ----------------
// Y written in flat packed layout [col=(bt*49+p)][512=(n*64+e)].
__global__ __launch_bounds__(512,2) void attn_kernel(const unsigned short* __restrict__ Qg,
    const unsigned short* __restrict__ Kg, const unsigned short* __restrict__ Vg,
    const float* __restrict__ bk, const float* __restrict__ bv,
    unsigned short* __restrict__ Yg){
  const int bid = blockIdx.x;
  const int bt = ((bid & 7) << 5) | (bid >> 3);
  const int b = bt >> 5, t = bt & 31, tid = threadIdx.x;
  const int n = __builtin_amdgcn_readfirstlane(tid >> 6);
  const int lane = tid & 63, g = lane >> 4, l15 = lane & 15, g4 = (lane >> 4)*4;
  const size_t bnt = ((size_t)(b*8 + n)*32 + t);
  const unsigned short* Qb = Qg + bnt*3136;
  s16x8 Qf[4][2];
  #pragma unroll
  for (int ni = 0; ni < 4; ++ni)
    #pragma unroll
    for (int ks = 0; ks < 2; ++ks)
      Qf[ni][ks] = *(const s16x8*)(Qb + (ni*16 + l15)*64 + ks*32 + g*8);
  const float* bkp = bk + n*64;
  f32x4 bkf[2][2];
  bkf[0][0] = *(const f32x4*)(bkp + g*8);      bkf[0][1] = *(const f32x4*)(bkp + g*8 + 4);
  bkf[1][0] = *(const f32x4*)(bkp + 32 + g*8); bkf[1][1] = *(const f32x4*)(bkp + 32 + g*8 + 4);
  float pad_l[4];
  #pragma unroll
  for (int ni = 0; ni < 4; ++ni){
    float s = 0.f;
    #pragma unroll
    for (int ks = 0; ks < 2; ++ks)
      #pragma unroll
      for (int h = 0; h < 2; ++h)
        #pragma unroll
        for (int j = 0; j < 4; ++j)
          s += bf2f((unsigned short)Qf[ni][ks][h*4+j]) * bkf[ks][h][j];
    s += __shfl_xor(s, 16); s += __shfl_xor(s, 32);
    pad_l[ni] = s;
  }
  float m_run[4], d_run[4];
  f32x4 Yacc[4][4];
  #pragma unroll
  for (int ni = 0; ni < 4; ++ni){
    m_run[ni] = -1e30f; d_run[ni] = 0.f;
    #pragma unroll
    for (int me = 0; me < 4; ++me) Yacc[me][ni] = 0.f;
  }
  int slo = 3 - t; if (slo < 0) slo = 0;
  int shi = 34 - t; if (shi > 6) shi = 6;
  for (int s = slo; s <= shi; ++s){
    const int tt = t + s - 3;
    const unsigned short* Kb = Kg + ((size_t)(b*8 + n)*32 + tt)*3136;
    const unsigned short* Vb = Vg + ((size_t)(b*8 + n)*32 + tt)*3328;
    f32x4 S[4][4];
    #pragma unroll
    for (int mi = 0; mi < 4; ++mi)
      #pragma unroll
      for (int ni = 0; ni < 4; ++ni) S[mi][ni] = 0.f;
    __builtin_amdgcn_s_setprio(1);
    #pragma unroll
    for (int ks = 0; ks < 2; ++ks)
      #pragma unroll
      for (int mi = 0; mi < 4; ++mi){
        s16x8 Kf = *(const s16x8*)(Kb + (mi*16 + l15)*64 + ks*32 + g*8);
        #pragma unroll
        for (int ni = 0; ni < 4; ++ni)
          S[mi][ni] = mfma16(Kf, Qf[ni][ks], S[mi][ni]);
      }
    __builtin_amdgcn_s_setprio(0);
    #pragma unroll
    for (int r = 0; r < 4; ++r){
      const bool bad = (g4 + r) >= 1;
      #pragma unroll
      for (int ni = 0; ni < 4; ++ni)
        S[3][ni][r] = bad ? -1e30f : S[3][ni][r];
    }
    #pragma unroll
    for (int ni = 0; ni < 4; ++ni){
      float mx = -1e30f;
      #pragma unroll
      for (int mi = 0; mi < 4; ++mi)
        #pragma unroll
        for (int r = 0; r < 4; ++r) mx = fmaxf(mx, S[mi][ni][r]);
      mx = fmaxf(mx, __shfl_xor(mx, 16));
      mx = fmaxf(mx, __shfl_xor(mx, 32));
      const float mn = fmaxf(m_run[ni], mx);
      const float rs = exp2f(m_run[ni] - mn);
      m_run[ni] = mn;
      float sum = 0.f;
      #pragma unroll
      for (int mi = 0; mi < 4; ++mi)
        #pragma unroll
        for (int r = 0; r < 4; ++r){
          float e = exp2f(S[mi][ni][r] - mn);
          S[mi][ni][r] = e; sum += e;
        }
      sum += __shfl_xor(sum, 16); sum += __shfl_xor(sum, 32);
      d_run[ni] = d_run[ni]*rs + sum;
      #pragma unroll
      for (int me = 0; me < 4; ++me) Yacc[me][ni] *= rs;
    }
    #pragma unroll
    for (int ks = 0; ks < 2; ++ks){
      s16x8 Pf[4];
      #pragma unroll
      for (int ni = 0; ni < 4; ++ni){
        f32x4 a = S[2*ks][ni], b2 = S[2*ks+1][ni];
        s16x8 pf;
        #pragma unroll
        for (int j = 0; j < 4; ++j){
          pf[j]   = (short)f2bf(a[j]);
          pf[4+j] = (short)f2bf(b2[j]);
        }
        Pf[ni] = pf;
      }
      __builtin_amdgcn_s_setprio(1);
      #pragma unroll
      for (int me = 0; me < 4; ++me){
        s16x4 vlo = *(const s16x4*)(Vb + (size_t)(me*16 + l15)*52 + ks*32 + g4);
        s16x4 vhi = *(const s16x4*)(Vb + (size_t)(me*16 + l15)*52 + ks*32 + 16 + g4);
        s16x8 Vf;
        #pragma unroll
        for (int j = 0; j < 4; ++j){ Vf[j] = vlo[j]; Vf[4+j] = vhi[j]; }
        #pragma unroll
        for (int ni = 0; ni < 4; ++ni)
          Yacc[me][ni] = mfma16(Vf, Pf[ni], Yacc[me][ni]);
      }
      __builtin_amdgcn_s_setprio(0);
    }
  }
  const int n_pad = slo + (6 - shi);
  f32x4 bvf[4];
  #pragma unroll
  for (int me = 0; me < 4; ++me)
    bvf[me] = *(const f32x4*)(bv + n*64 + me*16 + g4);
  unsigned short* Yb = Yg + (size_t)bt*49*512 + n*64;
  #pragma unroll
  for (int ni = 0; ni < 4; ++ni){
    float rs = 1.f, pw = 0.f, d = d_run[ni];
    if (n_pad > 0){
      const float mf = fmaxf(m_run[ni], pad_l[ni]);
      rs = exp2f(m_run[ni] - mf);
      pw = (float)(n_pad*49) * exp2f(pad_l[ni] - mf);
      d = d_run[ni]*rs + pw;
    }
    const float inv = 1.f/d;
    const int p = ni*16 + l15;
    if (p < 49){
      #pragma unroll
      for (int me = 0; me < 4; ++me){
        s16x4 u;
        #pragma unroll
        for (int r = 0; r < 4; ++r)
          u[r] = (short)f2bf((Yacc[me][ni][r]*rs + pw*bvf[me][r])*inv);
        *(s16x4*)(Yb + (size_t)p*512 + me*16 + g4) = u;
      }
    }
  }
}

// ---------------- output projection: LDS-free 1-wave 64x64 tiles ----------------
// Wo2(512x512) x Yg(512x12544) + residual + scatter to out.
__global__ __launch_bounds__(64,2) void out_gemm(const unsigned short* __restrict__ Wo2,
    const unsigned short* __restrict__ Yg, const unsigned short* __restrict__ Xt,
    const float* __restrict__ scale, const float* __restrict__ shift,
    const float* __restrict__ bo_sum, float* __restrict__ out){
  const int bid = blockIdx.x;
  const int id = (bid & 7)*196 + (bid >> 3);   // 1568 = 8*196, bijective
  const int mt = id % 8, nt = id / 8;          // mt fastest: B panel reused
  const int m0 = mt*64, n0 = nt*64;
  const int lane = threadIdx.x & 63, l15 = lane & 15, g = lane >> 4, g4 = (lane >> 4)*4;
  const unsigned short* Ab = Wo2 + (size_t)(m0 + l15)*512 + g*8;
  const unsigned short* Bb = Yg  + (size_t)(n0 + l15)*512 + g*8;
  f32x4 acc[4][4];
  #pragma unroll
  for (int mi = 0; mi < 4; ++mi)
    #pragma unroll
    for (int ni = 0; ni < 4; ++ni) acc[mi][ni] = 0.f;
  #pragma unroll 4
  for (int ks = 0; ks < 16; ++ks){
    s16x8 Af[4], Bf[4];
    #pragma unroll
    for (int mi = 0; mi < 4; ++mi) Af[mi] = *(const s16x8*)(Ab + mi*8192 + ks*32);
    #pragma unroll
    for (int ni = 0; ni < 4; ++ni) Bf[ni] = *(const s16x8*)(Bb + ni*8192 + ks*32);
    #pragma unroll
    for (int mi = 0; mi < 4; ++mi)
      #pragma unroll
      for (int ni = 0; ni < 4; ++ni)
        acc[mi][ni] = mfma16(Af[mi], Bf[ni], acc[mi][ni]);
  }
  int colv[4]; size_t obase[4];
  #pragma unroll
  for (int ni = 0; ni < 4; ++ni){
    const int col = n0 + ni*16 + l15;
    const int btc = col / 49, p = col - btc*49;
    const int b = btc >> 5, t = btc & 31;
    colv[ni] = col;
    obase[ni] = (size_t)b*802816 + t*49 + p;
  }
  #pragma unroll
  for (int mi = 0; mi < 4; ++mi){
    const int c0 = m0 + mi*16 + g4;
    const f32x4 bs = *(const f32x4*)(bo_sum + c0);
    const f32x4 sc = *(const f32x4*)(scale + c0);
    const f32x4 sh = *(const f32x4*)(shift + c0);
    #pragma unroll
    for (int ni = 0; ni < 4; ++ni){
      s16x4 xb = *(const s16x4*)(Xt + (size_t)colv[ni]*512 + c0);
      #pragma unroll
      for (int r = 0; r < 4; ++r){
        out[obase[ni] + (size_t)(c0 + r)*1568] =
            acc[mi][ni][r] + bs[r] + sc[r]*bf2f((unsigned short)xb[r]) + sh[r];
      }
    }
  }
}

extern "C" void kernel_launch(void* const* d_in, const int* in_sizes, int n_in_,
                              void* d_out, int out_size, void* d_ws, size_t ws_size,
                              hipStream_t stream){
  const float* x     = (const float*)d_in[0];
  const float* gamma = (const float*)d_in[1];
  const float* beta  = (const float*)d_in[2];
  const float* Wq    = (const float*)d_in[3];
  const float* bq    = (const float*)d_in[4];
  const float* Wk    = (const float*)d_in[5];
  const float* bk    = (const float*)d_in[6];
  const float* Wv    = (const float*)d_in[7];
  const float* bv    = (const float*)d_in[8];
  const float* Wo    = (const float*)d_in[9];
  const float* bo    = (const float*)d_in[10];
  float* out = (float*)d_out;

  char* ws = (char*)d_ws;
  float* scale    = (float*)ws;          // 512
  float* shift    = scale + 512;         // 512
  float* bo_sum   = shift + 512;         // 512
  float* biasAll  = bo_sum + 512;        // 1536
  float* partials = biasAll + 1536;      // 256*512*2 = 262144
  unsigned short* Wall = (unsigned short*)(ws + 1064960);
  const size_t PAD = 16384;
  unsigned short* Wo2 = Wall + 786432;
  unsigned short* Xt  = Wo2 + 262144;     // 12544*512
  unsigned short* Qg  = Xt + 6422528;
  unsigned short* Kg  = Qg + 6422528 + PAD;
  unsigned short* Vg  = Kg + 6422528 + PAD;
  unsigned short* Yg  = Vg + 6815744 + PAD;   // 12544*512 packed

  hipLaunchKernelGGL(xt_kernel, dim3(256), dim3(256), 0, stream, x, Xt, partials);
  hipLaunchKernelGGL(stats2_kernel, dim3(8), dim3(256), 0, stream,
                     partials, gamma, beta, scale, shift);
  hipLaunchKernelGGL(prep_kernel, dim3(2241), dim3(512), 0, stream,
                     Wq, Wk, Wv, Wo, bo, bq, bk, bv, scale, shift,
                     Wall, Wo2, bo_sum, biasAll);
  hipLaunchKernelGGL(qkv_gemm, dim3(1176), dim3(256), 0, stream,
                     Wall, Xt, biasAll, Qg, Kg, Vg);
  hipLaunchKernelGGL(attn_kernel, dim3(256), dim3(512), 0, stream,
                     Qg, Kg, Vg, bk, bv, Yg);
  hipLaunchKernelGGL(out_gemm, dim3(1568), dim3(64), 0, stream,
                     Wo2, Yg, Xt, scale, shift, bo_sum, out);
}

// Round 8
// 145.475 us; speedup vs baseline: 1.3407x; 1.3407x over previous
//
#include <hip/hip_runtime.h>
#include <hip/hip_bf16.h>

// Shapes: B=8 C=512 T=32 H=W=7 P=49 N=8 E=64 K_WIN=7
// x: (B,C,T,H,W) fp32; out same fp32.
// BatchNorm folded into GEMM weights (W*scale, bias+W@shift); Q rows also
// pre-scaled by log2e. Columns packed to 256*49=12544.
// Q-projection and output-projection+residual are fused into the attention
// kernel (block = bt, wave = head); only K/V go through the standalone GEMM.

typedef float f32x4 __attribute__((ext_vector_type(4)));
typedef float f32x2 __attribute__((ext_vector_type(2)));
typedef short s16x8 __attribute__((ext_vector_type(8)));
typedef short s16x4 __attribute__((ext_vector_type(4)));
typedef __bf16 bf16x8 __attribute__((ext_vector_type(8)));

static __device__ __forceinline__ float bf2f(unsigned short u){
  union { unsigned int i; float f; } x; x.i = ((unsigned int)u) << 16; return x.f;
}
static __device__ __forceinline__ unsigned short f2bf(float f){
  union { __hip_bfloat16 h; unsigned short u; } x; x.h = __float2bfloat16(f); return x.u;
}
static __device__ __forceinline__ f32x4 mfma16(s16x8 a, s16x8 b, f32x4 c){
  return __builtin_amdgcn_mfma_f32_16x16x32_bf16(
      __builtin_bit_cast(bf16x8, a), __builtin_bit_cast(bf16x8, b), c, 0, 0, 0);
}
static __device__ __forceinline__ void gload16(const unsigned short* g, unsigned short* l){
  __builtin_amdgcn_global_load_lds(
      (const __attribute__((address_space(1))) unsigned int*)g,
      (__attribute__((address_space(3))) unsigned int*)l, 16, 0, 0);
}

// ---------------- x -> Xt[bt*49+p][c] bf16  +  per-bt channel partial sums ----------------
__global__ __launch_bounds__(256) void xt_kernel(const float* __restrict__ x,
    unsigned short* __restrict__ Xt, float* __restrict__ partials){
  __shared__ unsigned short Xc[512][53];
  const int bt = blockIdx.x, b = bt >> 5, t = bt & 31, tid = threadIdx.x;
  const float* xb = x + (size_t)b*802816 + t*49;
  for (int i = tid; i < 512*49; i += 256){
    int c = i / 49, p = i - c*49;
    Xc[c][p] = f2bf(xb[(size_t)c*1568 + p]);
  }
  __syncthreads();
  unsigned short* dst = Xt + (size_t)bt*49*512;
  for (int i = tid; i < 49*64; i += 256){
    int p = i >> 6, c0 = (i & 63) << 3;
    s16x8 v;
    #pragma unroll
    for (int j = 0; j < 8; ++j) v[j] = (short)Xc[c0+j][p];
    *(s16x8*)(dst + p*512 + c0) = v;
  }
  for (int c = tid; c < 512; c += 256){
    float s1 = 0.f, s2 = 0.f;
    #pragma unroll 7
    for (int p = 0; p < 49; ++p){
      float f = bf2f(Xc[c][p]);
      s1 += f; s2 += f*f;
    }
    f32x2 o; o[0] = s1; o[1] = s2;
    *(f32x2*)(partials + ((size_t)bt*512 + c)*2) = o;
  }
}

// ---------------- reduce 256 partials -> scale/shift ----------------
__global__ __launch_bounds__(256) void stats2_kernel(const float* __restrict__ partials,
    const float* __restrict__ gamma, const float* __restrict__ beta,
    float* __restrict__ scale, float* __restrict__ shift){
  __shared__ float R1[4][64], R2[4][64];
  const int h = blockIdx.x, tid = threadIdx.x;
  const int r = tid >> 6, co = tid & 63;
  const int c = h*64 + co;
  float s1 = 0.f, s2 = 0.f;
  for (int k = r; k < 256; k += 4){
    f32x2 v = *(const f32x2*)(partials + ((size_t)k*512 + c)*2);
    s1 += v[0]; s2 += v[1];
  }
  R1[r][co] = s1; R2[r][co] = s2;
  __syncthreads();
  if (tid < 64){
    float t1 = R1[0][tid]+R1[1][tid]+R1[2][tid]+R1[3][tid];
    float t2 = R2[0][tid]+R2[1][tid]+R2[2][tid]+R2[3][tid];
    const int cc = h*64 + tid;
    const float inv = 1.f/12544.f;
    float mean = t1*inv;
    float var  = t2*inv - mean*mean;
    float sc = gamma[cc]*rsqrtf(var + 1e-5f);
    scale[cc] = sc;
    shift[cc] = beta[cc] - mean*sc;
  }
}

// ---------------- prep: pack weights (scale folded, Q rows x log2e) + bias fold ----------------
__global__ __launch_bounds__(512) void prep_kernel(const float* __restrict__ Wq,
    const float* __restrict__ Wk, const float* __restrict__ Wv,
    const float* __restrict__ Wo, const float* __restrict__ bo,
    const float* __restrict__ bq, const float* __restrict__ bk,
    const float* __restrict__ bv,
    const float* __restrict__ scale, const float* __restrict__ shift,
    unsigned short* __restrict__ Wall, unsigned short* __restrict__ Wo2,
    float* __restrict__ bo_sum, float* __restrict__ biasAll){
  const float L2E = 1.4426950408889634f;
  const int bid = blockIdx.x;
  if (bid < 2049){
    int i = bid*512 + threadIdx.x;
    if (i < 786432){
      const float* W = (i < 262144) ? Wq : (i < 524288 ? Wk : Wv);
      float m = (i < 262144) ? L2E : 1.f;
      Wall[i] = f2bf(W[i & 262143] * scale[i & 511] * m);
    } else if (i < 1048576){
      int j = i - 786432;
      int c = j >> 9, k = j & 511, nn = k >> 6, e = k & 63;
      Wo2[j] = f2bf(Wo[((size_t)nn*512 + c)*64 + e] * 0.125f);
    } else if (i < 1049088){
      int c = i - 1048576;
      float s = 0.f;
      #pragma unroll
      for (int nn = 0; nn < 8; ++nn) s += bo[nn*512 + c];
      bo_sum[c] = s * 0.125f;
    }
  } else {
    const int row = (bid - 2049)*8 + (threadIdx.x >> 6);
    const int lane = threadIdx.x & 63;
    const float* W    = row < 512 ? Wq : (row < 1024 ? Wk : Wv);
    const float* bsrc = row < 512 ? bq : (row < 1024 ? bk : bv);
    const int r = row & 511;
    const float* Wr = W + (size_t)r*512;
    float s = 0.f;
    #pragma unroll
    for (int j = 0; j < 8; ++j) s += Wr[lane + 64*j]*shift[lane + 64*j];
    #pragma unroll
    for (int off = 32; off > 0; off >>= 1) s += __shfl_down(s, off);
    if (lane == 0) biasAll[row] = (bsrc[r] + s) * (row < 512 ? L2E : 1.f);
  }
}

// ---------------- KV GEMM: WallKV(1024x512) x Xt^T(512x12544), 128x128, 2-deep ----------------
__global__ __launch_bounds__(256) void kv_gemm(const unsigned short* __restrict__ Wall,
    const unsigned short* __restrict__ Xt, const float* __restrict__ biasAll,
    unsigned short* __restrict__ Kg, unsigned short* __restrict__ Vg){
  __shared__ unsigned short As[2][4096];
  __shared__ unsigned short Bs[2][4096];
  const int bid = blockIdx.x;
  const int id = (bid & 7)*98 + (bid >> 3);    // 784 = 8*98, bijective
  const int bm = id & 7, bn = id >> 3;         // 8 x 98
  const int m0 = bm*128, n0 = bn*128;
  const int tid = threadIdx.x;
  const int w = __builtin_amdgcn_readfirstlane(tid >> 6);
  const int lane = tid & 63, l15 = lane & 15, g = lane >> 4, g4 = (lane >> 4)*4;
  const int wm = w >> 1, wn = w & 1;
  const int cA = w*128 + lane;
  int offA[4], offB[4];
  #pragma unroll
  for (int mi = 0; mi < 4; ++mi){
    int row = wm*64 + mi*16 + l15;
    offA[mi] = row*32 + ((g ^ ((row>>1)&3))<<3);
  }
  #pragma unroll
  for (int ni = 0; ni < 4; ++ni){
    int col = wn*64 + ni*16 + l15;
    offB[ni] = col*32 + ((g ^ ((col>>1)&3))<<3);
  }
  f32x4 acc[4][4];
  #pragma unroll
  for (int mi = 0; mi < 4; ++mi)
    #pragma unroll
    for (int ni = 0; ni < 4; ++ni) acc[mi][ni] = 0.f;

  const unsigned short* Akv = Wall + 512*512;   // skip Q rows
  auto stage = [&](int bufi, int ks){
    #pragma unroll
    for (int it = 0; it < 2; ++it){
      int c = cA + it*64;
      int row = c >> 2, slot = c & 3;
      int ko = ks*32 + ((slot ^ ((row>>1)&3))<<3);
      gload16(Akv + (size_t)(m0 + row)*512 + ko, &As[bufi][(w*128 + it*64)*8]);
      gload16(Xt  + (size_t)(n0 + row)*512 + ko, &Bs[bufi][(w*128 + it*64)*8]);
    }
  };
  auto compute = [&](int bufi){
    s16x8 Af[4], Bf[4];
    #pragma unroll
    for (int mi = 0; mi < 4; ++mi) Af[mi] = *(const s16x8*)&As[bufi][offA[mi]];
    #pragma unroll
    for (int ni = 0; ni < 4; ++ni) Bf[ni] = *(const s16x8*)&Bs[bufi][offB[ni]];
    #pragma unroll
    for (int mi = 0; mi < 4; ++mi)
      #pragma unroll
      for (int ni = 0; ni < 4; ++ni)
        acc[mi][ni] = mfma16(Af[mi], Bf[ni], acc[mi][ni]);
  };

  stage(0, 0);
  __syncthreads();
  #pragma unroll 1
  for (int kk = 0; kk < 8; ++kk){
    stage(1, kk*2 + 1);
    compute(0);
    __syncthreads();
    if (kk < 7) stage(0, kk*2 + 2);
    compute(1);
    __syncthreads();
  }

  // epilogue: qb 0..15 -> which (0=K,1=V), head n
  const int qb = bm*2 + wm;
  const int which = qb >> 3, n = qb & 7;
  f32x4 bb[4];
  #pragma unroll
  for (int mi = 0; mi < 4; ++mi)
    bb[mi] = *(const f32x4*)(biasAll + 512 + qb*64 + mi*16 + g4);
  #pragma unroll
  for (int ni = 0; ni < 4; ++ni){
    const int col = n0 + wn*64 + ni*16 + l15;
    const int btc = col / 49, p = col - btc*49;
    const size_t bnt = ((size_t)((btc >> 5)*8 + n)*32 + (btc & 31));
    #pragma unroll
    for (int mi = 0; mi < 4; ++mi){
      const int e0 = mi*16 + g4;
      f32x4 v = acc[mi][ni] + bb[mi];
      if (which == 0){
        s16x4 u;
        #pragma unroll
        for (int r = 0; r < 4; ++r) u[r] = (short)f2bf(v[r]);
        *(s16x4*)(Kg + (bnt*49 + p)*64 + e0) = u;
      } else {
        #pragma unroll
        for (int r = 0; r < 4; ++r)
          Vg[bnt*3328 + (size_t)(e0 + r)*52 + p] = f2bf(v[r]);
      }
    }
  }
}

// ---------------- fused: Q-proj + local attention + out-proj + residual ----------------
// block = bt (XCD-swizzled), wave = head. LDS: Xs (Xt tile, swizzled) + Qs (Q then Y).
__global__ __launch_bounds__(512) void attn_fused(
    const unsigned short* __restrict__ Wall, const unsigned short* __restrict__ Wo2,
    const unsigned short* __restrict__ Xt,
    const unsigned short* __restrict__ Kg, const unsigned short* __restrict__ Vg,
    const float* __restrict__ biasAll, const float* __restrict__ bk,
    const float* __restrict__ bv, const float* __restrict__ scale,
    const float* __restrict__ shift, const float* __restrict__ bo_sum,
    float* __restrict__ out){
  __shared__ unsigned short Xs[64*512];   // [p][c], 16B-chunk q XOR (p&7)
  __shared__ unsigned short Qs[64*512];   // [p][ne], same swizzle; Q then Y
  const int bid = blockIdx.x;
  const int bt = ((bid & 7) << 5) | (bid >> 3);
  const int b = bt >> 5, t = bt & 31, tid = threadIdx.x;
  const int n = __builtin_amdgcn_readfirstlane(tid >> 6);
  const int lane = tid & 63, g = lane >> 4, l15 = lane & 15, g4 = (lane >> 4)*4;

  // ---- stage Xt tile -> Xs (linear dest, pre-swizzled source) ----
  #pragma unroll
  for (int it = 0; it < 8; ++it){
    int s = it*512 + tid;              // chunk id 0..4095
    int p = s >> 6, qs = s & 63;
    int qsrc = qs ^ (p & 7);
    int pc = p < 49 ? p : 48;          // clamp (rows >=49 unused garbage)
    gload16(Xt + ((size_t)(bt*49 + pc))*512 + qsrc*8, &Xs[s*8]);
  }
  asm volatile("s_waitcnt vmcnt(0)" ::: "memory");
  __syncthreads();

  // ---- Q-GEMM: Q[e 64][p 64] = Wq'[n](64x512) x Xs ----
  {
    f32x4 qacc[4][4];
    #pragma unroll
    for (int mi = 0; mi < 4; ++mi)
      #pragma unroll
      for (int ni = 0; ni < 4; ++ni) qacc[mi][ni] = 0.f;
    #pragma unroll 4
    for (int ks = 0; ks < 16; ++ks){
      s16x8 Bf[4];
      #pragma unroll
      for (int ni = 0; ni < 4; ++ni){
        int p = ni*16 + l15, q = ks*4 + g;
        Bf[ni] = *(const s16x8*)&Xs[p*512 + ((q ^ (p&7))<<3)];
      }
      #pragma unroll
      for (int mi = 0; mi < 4; ++mi){
        s16x8 Af = *(const s16x8*)(Wall + (size_t)(n*64 + mi*16 + l15)*512 + ks*32 + g*8);
        #pragma unroll
        for (int ni = 0; ni < 4; ++ni)
          qacc[mi][ni] = mfma16(Af, Bf[ni], qacc[mi][ni]);
      }
    }
    #pragma unroll
    for (int mi = 0; mi < 4; ++mi){
      const int e = mi*16 + g4;
      const f32x4 bq4 = *(const f32x4*)(biasAll + n*64 + e);
      const int ne = n*64 + e, q = ne >> 3;
      #pragma unroll
      for (int ni = 0; ni < 4; ++ni){
        const int p = ni*16 + l15;
        f32x4 v = qacc[mi][ni] + bq4;
        s16x4 u;
        #pragma unroll
        for (int r = 0; r < 4; ++r) u[r] = (short)f2bf(v[r]);
        *(s16x4*)&Qs[p*512 + ((q ^ (p&7))<<3) + (ne & 7)] = u;
      }
    }
  }
  // ---- load Q fragments back (wave-private region; lgkm ordering by compiler) ----
  s16x8 Qf[4][2];
  #pragma unroll
  for (int ni = 0; ni < 4; ++ni)
    #pragma unroll
    for (int ks = 0; ks < 2; ++ks){
      const int p = ni*16 + l15, q = n*8 + ks*4 + g;
      Qf[ni][ks] = *(const s16x8*)&Qs[p*512 + ((q ^ (p&7))<<3)];
    }

  const float* bkp = bk + n*64;
  f32x4 bkf[2][2];
  bkf[0][0] = *(const f32x4*)(bkp + g*8);      bkf[0][1] = *(const f32x4*)(bkp + g*8 + 4);
  bkf[1][0] = *(const f32x4*)(bkp + 32 + g*8); bkf[1][1] = *(const f32x4*)(bkp + 32 + g*8 + 4);
  float pad_l[4];
  #pragma unroll
  for (int ni = 0; ni < 4; ++ni){
    float s = 0.f;
    #pragma unroll
    for (int ks = 0; ks < 2; ++ks)
      #pragma unroll
      for (int h = 0; h < 2; ++h)
        #pragma unroll
        for (int j = 0; j < 4; ++j)
          s += bf2f((unsigned short)Qf[ni][ks][h*4+j]) * bkf[ks][h][j];
    s += __shfl_xor(s, 16); s += __shfl_xor(s, 32);
    pad_l[ni] = s;
  }
  float m_run[4], d_run[4];
  f32x4 Yacc[4][4];
  #pragma unroll
  for (int ni = 0; ni < 4; ++ni){
    m_run[ni] = -1e30f; d_run[ni] = 0.f;
    #pragma unroll
    for (int me = 0; me < 4; ++me) Yacc[me][ni] = 0.f;
  }
  int slo = 3 - t; if (slo < 0) slo = 0;
  int shi = 34 - t; if (shi > 6) shi = 6;
  for (int s = slo; s <= shi; ++s){
    const int tt = t + s - 3;
    const unsigned short* Kb = Kg + ((size_t)(b*8 + n)*32 + tt)*3136;
    const unsigned short* Vb = Vg + ((size_t)(b*8 + n)*32 + tt)*3328;
    f32x4 S[4][4];
    #pragma unroll
    for (int mi = 0; mi < 4; ++mi)
      #pragma unroll
      for (int ni = 0; ni < 4; ++ni) S[mi][ni] = 0.f;
    __builtin_amdgcn_s_setprio(1);
    #pragma unroll
    for (int ks = 0; ks < 2; ++ks)
      #pragma unroll
      for (int mi = 0; mi < 4; ++mi){
        s16x8 Kf = *(const s16x8*)(Kb + (mi*16 + l15)*64 + ks*32 + g*8);
        #pragma unroll
        for (int ni = 0; ni < 4; ++ni)
          S[mi][ni] = mfma16(Kf, Qf[ni][ks], S[mi][ni]);
      }
    __builtin_amdgcn_s_setprio(0);
    #pragma unroll
    for (int r = 0; r < 4; ++r){
      const bool bad = (g4 + r) >= 1;
      #pragma unroll
      for (int ni = 0; ni < 4; ++ni)
        S[3][ni][r] = bad ? -1e30f : S[3][ni][r];
    }
    #pragma unroll
    for (int ni = 0; ni < 4; ++ni){
      float mx = -1e30f;
      #pragma unroll
      for (int mi = 0; mi < 4; ++mi)
        #pragma unroll
        for (int r = 0; r < 4; ++r) mx = fmaxf(mx, S[mi][ni][r]);
      mx = fmaxf(mx, __shfl_xor(mx, 16));
      mx = fmaxf(mx, __shfl_xor(mx, 32));
      const float mn = fmaxf(m_run[ni], mx);
      const float rs = exp2f(m_run[ni] - mn);
      m_run[ni] = mn;
      float sum = 0.f;
      #pragma unroll
      for (int mi = 0; mi < 4; ++mi)
        #pragma unroll
        for (int r = 0; r < 4; ++r){
          float e = exp2f(S[mi][ni][r] - mn);
          S[mi][ni][r] = e; sum += e;
        }
      sum += __shfl_xor(sum, 16); sum += __shfl_xor(sum, 32);
      d_run[ni] = d_run[ni]*rs + sum;
      #pragma unroll
      for (int me = 0; me < 4; ++me) Yacc[me][ni] *= rs;
    }
    #pragma unroll
    for (int ks = 0; ks < 2; ++ks){
      s16x8 Pf[4];
      #pragma unroll
      for (int ni = 0; ni < 4; ++ni){
        f32x4 a = S[2*ks][ni], b2 = S[2*ks+1][ni];
        s16x8 pf;
        #pragma unroll
        for (int j = 0; j < 4; ++j){
          pf[j]   = (short)f2bf(a[j]);
          pf[4+j] = (short)f2bf(b2[j]);
        }
        Pf[ni] = pf;
      }
      __builtin_amdgcn_s_setprio(1);
      #pragma unroll
      for (int me = 0; me < 4; ++me){
        s16x4 vlo = *(const s16x4*)(Vb + (size_t)(me*16 + l15)*52 + ks*32 + g4);
        s16x4 vhi = *(const s16x4*)(Vb + (size_t)(me*16 + l15)*52 + ks*32 + 16 + g4);
        s16x8 Vf;
        #pragma unroll
        for (int j = 0; j < 4; ++j){ Vf[j] = vlo[j]; Vf[4+j] = vhi[j]; }
        #pragma unroll
        for (int ni = 0; ni < 4; ++ni)
          Yacc[me][ni] = mfma16(Vf, Pf[ni], Yacc[me][ni]);
      }
      __builtin_amdgcn_s_setprio(0);
    }
  }
  const int n_pad = slo + (6 - shi);
  f32x4 bvf[4];
  #pragma unroll
  for (int me = 0; me < 4; ++me)
    bvf[me] = *(const f32x4*)(bv + n*64 + me*16 + g4);
  // ---- Y -> Qs (own head's columns; overwrite Q region) ----
  #pragma unroll
  for (int ni = 0; ni < 4; ++ni){
    float rs = 1.f, pw = 0.f, d = d_run[ni];
    if (n_pad > 0){
      const float mf = fmaxf(m_run[ni], pad_l[ni]);
      rs = exp2f(m_run[ni] - mf);
      pw = (float)(n_pad*49) * exp2f(pad_l[ni] - mf);
      d = d_run[ni]*rs + pw;
    }
    const float inv = 1.f/d;
    const int p = ni*16 + l15;
    #pragma unroll
    for (int me = 0; me < 4; ++me){
      const int ne = n*64 + me*16 + g4, q = ne >> 3;
      s16x4 u;
      #pragma unroll
      for (int r = 0; r < 4; ++r)
        u[r] = (short)f2bf((Yacc[me][ni][r]*rs + pw*bvf[me][r])*inv);
      *(s16x4*)&Qs[p*512 + ((q ^ (p&7))<<3) + (ne & 7)] = u;
    }
  }
  __syncthreads();

  // ---- out-GEMM: wave owns c-rows n*64..n*64+63; out = Wo2 x Y + bo_sum + residual ----
  {
    f32x4 acc[4][4];
    #pragma unroll
    for (int mi = 0; mi < 4; ++mi)
      #pragma unroll
      for (int ni = 0; ni < 4; ++ni) acc[mi][ni] = 0.f;
    #pragma unroll 4
    for (int ks = 0; ks < 16; ++ks){
      s16x8 Bf[4];
      #pragma unroll
      for (int ni = 0; ni < 4; ++ni){
        int p = ni*16 + l15, q = ks*4 + g;
        Bf[ni] = *(const s16x8*)&Qs[p*512 + ((q ^ (p&7))<<3)];
      }
      #pragma unroll
      for (int mi = 0; mi < 4; ++mi){
        s16x8 Af = *(const s16x8*)(Wo2 + (size_t)(n*64 + mi*16 + l15)*512 + ks*32 + g*8);
        #pragma unroll
        for (int ni = 0; ni < 4; ++ni)
          acc[mi][ni] = mfma16(Af, Bf[ni], acc[mi][ni]);
      }
    }
    #pragma unroll
    for (int mi = 0; mi < 4; ++mi){
      const int c0 = n*64 + mi*16 + g4;
      const f32x4 bs = *(const f32x4*)(bo_sum + c0);
      const f32x4 sc = *(const f32x4*)(scale + c0);
      const f32x4 sh = *(const f32x4*)(shift + c0);
      const int q = c0 >> 3;
      #pragma unroll
      for (int ni = 0; ni < 4; ++ni){
        const int p = ni*16 + l15;
        if (p < 49){
          s16x4 xb = *(const s16x4*)&Xs[p*512 + ((q ^ (p&7))<<3) + (c0 & 7)];
          const size_t obase = (size_t)b*802816 + t*49 + p;
          #pragma unroll
          for (int r = 0; r < 4; ++r){
            out[obase + (size_t)(c0 + r)*1568] =
                acc[mi][ni][r] + bs[r] + sc[r]*bf2f((unsigned short)xb[r]) + sh[r];
          }
        }
      }
    }
  }
}

extern "C" void kernel_launch(void* const* d_in, const int* in_sizes, int n_in_,
                              void* d_out, int out_size, void* d_ws, size_t ws_size,
                              hipStream_t stream){
  const float* x     = (const float*)d_in[0];
  const float* gamma = (const float*)d_in[1];
  const float* beta  = (const float*)d_in[2];
  const float* Wq    = (const float*)d_in[3];
  const float* bq    = (const float*)d_in[4];
  const float* Wk    = (const float*)d_in[5];
  const float* bk    = (const float*)d_in[6];
  const float* Wv    = (const float*)d_in[7];
  const float* bv    = (const float*)d_in[8];
  const float* Wo    = (const float*)d_in[9];
  const float* bo    = (const float*)d_in[10];
  float* out = (float*)d_out;

  char* ws = (char*)d_ws;
  float* scale    = (float*)ws;          // 512
  float* shift    = scale + 512;         // 512
  float* bo_sum   = shift + 512;         // 512
  float* biasAll  = bo_sum + 512;        // 1536
  float* partials = biasAll + 1536;      // 256*512*2
  unsigned short* Wall = (unsigned short*)(ws + 1064960);
  const size_t PAD = 16384;
  unsigned short* Wo2 = Wall + 786432;
  unsigned short* Xt  = Wo2 + 262144;     // 12544*512
  unsigned short* Kg  = Xt + 6422528 + PAD;
  unsigned short* Vg  = Kg + 6422528 + PAD;

  hipLaunchKernelGGL(xt_kernel, dim3(256), dim3(256), 0, stream, x, Xt, partials);
  hipLaunchKernelGGL(stats2_kernel, dim3(8), dim3(256), 0, stream,
                     partials, gamma, beta, scale, shift);
  hipLaunchKernelGGL(prep_kernel, dim3(2241), dim3(512), 0, stream,
                     Wq, Wk, Wv, Wo, bo, bq, bk, bv, scale, shift,
                     Wall, Wo2, bo_sum, biasAll);
  hipLaunchKernelGGL(kv_gemm, dim3(784), dim3(256), 0, stream,
                     Wall, Xt, biasAll, Kg, Vg);
  hipLaunchKernelGGL(attn_fused, dim3(256), dim3(512), 0, stream,
                     Wall, Wo2, Xt, Kg, Vg, biasAll, bk, bv,
                     scale, shift, bo_sum, out);
}